// Round 3
// baseline (3955.735 us; speedup 1.0000x reference)
//
#include <hip/hip_runtime.h>
#include <hip/hip_bf16.h>

#define N_VOX 150000
#define CH 32
#define KVOL 27
#define NCLS 20
#define TOT (KVOL * N_VOX)          // 4,050,000
#define MPAD 150016
#define NPART 586                   // MPAD / 256
#define BCAP 576                    // per-wave bucket capacity (mean 432, +6.9 sigma)
#define WG_U32 (KVOL * 512)         // 13824 u32 per prepped weight set

typedef __attribute__((ext_vector_type(4))) float f32x4;
typedef __attribute__((ext_vector_type(8))) short short8;

#define WSYNC() asm volatile("s_waitcnt lgkmcnt(0)" ::: "memory")

__device__ __forceinline__ unsigned int pk_bf16(float a, float b) {
  unsigned int ua = __float_as_uint(a), ub = __float_as_uint(b);
  ua = ua + 0x7FFFu + ((ua >> 16) & 1u);     // RNE
  ub = ub + 0x7FFFu + ((ub >> 16) & 1u);
  return (ub & 0xFFFF0000u) | (ua >> 16);
}
__device__ __forceinline__ float bf_lo(unsigned int u) { return __uint_as_float(u << 16); }
__device__ __forceinline__ float bf_hi(unsigned int u) { return __uint_as_float(u & 0xFFFF0000u); }

// ============================ rulebook inversion ============================

__global__ __launch_bounds__(256) void k_hist(const int* __restrict__ sidx,
                                              int* __restrict__ cnt) {
  int e = blockIdx.x * 256 + threadIdx.x;
  if (e < TOT) atomicAdd(&cnt[sidx[e]], 1);
}

__global__ __launch_bounds__(256) void k_scan1(const int* __restrict__ cnt,
                                               int* __restrict__ tmp,
                                               int* __restrict__ part) {
  __shared__ int sb[256];
  int t = threadIdx.x;
  int gt = blockIdx.x * 256 + t;
  int v = cnt[gt];
  sb[t] = v;
  __syncthreads();
  for (int s = 1; s < 256; s <<= 1) {
    int a = (t >= s) ? sb[t - s] : 0;
    __syncthreads();
    sb[t] += a;
    __syncthreads();
  }
  tmp[gt] = sb[t] - v;
  if (t == 255) part[blockIdx.x] = sb[t];
}

__global__ __launch_bounds__(1024) void k_scan2(int* __restrict__ part) {
  __shared__ int sb[1024];
  int t = threadIdx.x;
  int v = (t < NPART) ? part[t] : 0;
  sb[t] = v;
  __syncthreads();
  for (int s = 1; s < 1024; s <<= 1) {
    int a = (t >= s) ? sb[t - s] : 0;
    __syncthreads();
    sb[t] += a;
    __syncthreads();
  }
  if (t < NPART) part[t] = sb[t] - v;
}

__global__ __launch_bounds__(256) void k_scan3(const int* __restrict__ tmp,
                                               const int* __restrict__ part,
                                               int* __restrict__ off) {
  int gt = blockIdx.x * 256 + threadIdx.x;
  off[gt] = tmp[gt] + part[blockIdx.x];
}

__global__ __launch_bounds__(256) void k_fill(const int* __restrict__ gidx,
                                              const int* __restrict__ sidx,
                                              const int* __restrict__ off,
                                              int* __restrict__ cur,
                                              int* __restrict__ pl) {
  int e = blockIdx.x * 256 + threadIdx.x;
  if (e >= TOT) return;
  int k = e / N_VOX;
  int s = sidx[e];
  int pos = atomicAdd(&cur[s], 1);
  pl[off[s] + pos] = (gidx[e] << 5) | k;
}

// ============================ weight prep (f32 -> B-frag bf16) ==============
// out[i]: i = k*512 + h*256 + l*4 + w  ->  u32 holding bf16 pair
//   (W[k][ci0][co], W[k][ci0+1][co]),  ci0 = 8*(l>>4)+2w, co = (l&15)+16h
__global__ __launch_bounds__(256) void k_wprep(const float* __restrict__ W,
                                               unsigned int* __restrict__ out) {
  int i = blockIdx.x * 256 + threadIdx.x;
  if (i >= WG_U32) return;
  int k = i >> 9, r = i & 511;
  int h = r >> 8, l = (r >> 2) & 63, w = r & 3;
  int ci0 = ((l >> 4) << 3) + (w << 1);
  int co = (l & 15) + (h << 4);
  const float* wk = W + k * 1024;
  out[i] = pk_bf16(wk[ci0 * 32 + co], wk[(ci0 + 1) * 32 + co]);
}

// ============================ f32 -> bf16 activation convert ================
__global__ __launch_bounds__(256) void k_tobf(const float4* __restrict__ in4,
                                              uint4* __restrict__ out4) {
  int i = blockIdx.x * 256 + threadIdx.x;
  if (i >= (N_VOX * CH) / 8) return;   // 600000
  float4 f0 = in4[i * 2], f1 = in4[i * 2 + 1];
  uint4 o;
  o.x = pk_bf16(f0.x, f0.y); o.y = pk_bf16(f0.z, f0.w);
  o.z = pk_bf16(f1.x, f1.y); o.w = pk_bf16(f1.z, f1.w);
  out4[i] = o;
}

// ============================ MFMA conv kernel ==============================
// Block = 256 thr = 4 waves. Each wave owns 16 output rows:
//  1) bucket its CSR entries by k into LDS (counting sort, LDS atomics)
//  2) per k, per 16-entry chunk: stage gathered bf16 rows into swizzled A-tile,
//     2x mfma_f32_16x16x32_bf16 vs W[k] B-frags, ds_add scatter into f32 accum
//  3) fused bias+ReLU, coalesced bf16 row write. No global atomics.
__global__ __launch_bounds__(256, 2) void k_conv(
    const uint4* __restrict__ src4, unsigned int* __restrict__ dst,
    const int* __restrict__ off, const int* __restrict__ pl,
    const uint4* __restrict__ Wg4, const float* __restrict__ bias) {
  __shared__ uint4 sW4[KVOL * 128];              // 55296 B, B-frag order
  __shared__ float sAcc[4][528];                 // 16 x 33 f32 per wave
  __shared__ uint4 sA4[4][64];                   // A-tile 16x32 bf16, swizzled
  __shared__ unsigned int sBkt[4][BCAP];         // (gi<<4)|lrow
  __shared__ int sKcnt[4][32], sKbase[4][32], sKcur[4][32];

  const int tid = threadIdx.x;
  for (int i = tid; i < KVOL * 128; i += 256) sW4[i] = Wg4[i];
  __syncthreads();

  const int wv = tid >> 6, l = tid & 63;
  const int r0 = (blockIdx.x * 4 + wv) * 16;

  float* acc_s = sAcc[wv];
  uint4* A4 = sA4[wv];
  unsigned int* bkt = sBkt[wv];
  int* kcnt = sKcnt[wv]; int* kbase = sKbase[wv]; int* kcur = sKcur[wv];

  for (int i = l; i < 528; i += 64) acc_s[i] = 0.f;
  if (l < 32) kcnt[l] = 0;
  WSYNC();

  // ---- bucket by k: count, scan, place (4 lanes per row) ----
  const int rr_ = l >> 2, jj = l & 3;
  const int row_g = r0 + rr_;
  int eb = 0, ee = 0;
  if (row_g < N_VOX) { eb = off[row_g]; ee = off[row_g + 1]; }

  for (int i = eb + jj; i < ee; i += 4) atomicAdd(&kcnt[pl[i] & 31], 1);
  WSYNC();
  if (l == 0) {
    int s = 0;
    for (int k = 0; k < KVOL; k++) { kbase[k] = s; kcur[k] = s; s += kcnt[k]; }
  }
  WSYNC();
  for (int i = eb + jj; i < ee; i += 4) {
    int p = pl[i];
    int pos = atomicAdd(&kcur[p & 31], 1);
    if (pos < BCAP) bkt[pos] = (unsigned int)((((unsigned int)p >> 5) << 4) | (unsigned int)rr_);
  }
  WSYNC();

  // ---- per-k MFMA chunks ----
  const f32x4 cz = {0.f, 0.f, 0.f, 0.f};
  const int e_ = l >> 2, b_ = l & 3;               // staging: 4 lanes per entry
  const int am = l & 15, ab = (l >> 4) ^ (l & 3);  // A-frag read (XOR swizzle)
  const int e0 = (l >> 4) << 2, co = l & 15;       // C scatter

  for (int k = 0; k < KVOL; k++) {
    int base = kbase[k];
    int kend = base + kcnt[k];
    if (kend > BCAP) kend = BCAP;
    for (int cb = base; cb < kend; cb += 16) {
      WSYNC();                                     // prior chunk's A reads done
      int slot = cb + e_;
      uint4 val = {0u, 0u, 0u, 0u};
      if (slot < kend) {
        int gi = (int)(bkt[slot] >> 4);
        val = src4[gi * 4 + b_];
      }
      A4[(e_ << 2) + (b_ ^ (e_ & 3))] = val;
      WSYNC();
      uint4 av = A4[(am << 2) + ab];
      uint4 bv0 = sW4[k * 128 + l];
      uint4 bv1 = sW4[k * 128 + 64 + l];
      union { uint4 u; short8 s; } ua, ub0, ub1;
      ua.u = av; ub0.u = bv0; ub1.u = bv1;
      f32x4 c0 = __builtin_amdgcn_mfma_f32_16x16x32_bf16(ua.s, ub0.s, cz, 0, 0, 0);
      f32x4 c1 = __builtin_amdgcn_mfma_f32_16x16x32_bf16(ua.s, ub1.s, cz, 0, 0, 0);
#pragma unroll
      for (int r = 0; r < 4; r++) {
        int s2 = cb + e0 + r;
        if (s2 < kend) {
          int lrow = (int)(bkt[s2] & 15u);
          atomicAdd(&acc_s[lrow * 33 + co], c0[r]);
          atomicAdd(&acc_s[lrow * 33 + co + 16], c1[r]);
        }
      }
    }
  }
  WSYNC();

  // ---- epilogue: bias + ReLU + bf16 pack, coalesced row write ----
  const int orow = r0 + (l >> 2);
  if (orow < N_VOX) {
    unsigned int ov[4];
#pragma unroll
    for (int w = 0; w < 4; w++) {
      int cp = ((l & 3) << 3) + (w << 1);
      float x0 = acc_s[(l >> 2) * 33 + cp] + bias[cp];
      float x1 = acc_s[(l >> 2) * 33 + cp + 1] + bias[cp + 1];
      x0 = fmaxf(x0, 0.f); x1 = fmaxf(x1, 0.f);
      ov[w] = pk_bf16(x0, x1);
    }
    uint4 o = {ov[0], ov[1], ov[2], ov[3]};
    ((uint4*)dst)[orow * 4 + (l & 3)] = o;
  }
}

// ============================ logits kernel (bf16 inputs) ===================
__global__ __launch_bounds__(256) void k_logits(
    const uint4* __restrict__ A4, const uint4* __restrict__ B4,
    const float* __restrict__ Wl, const float* __restrict__ bl,
    float* __restrict__ out) {
  __shared__ float sWl[CH * NCLS];
  __shared__ float sbl[NCLS];
  int tid = threadIdx.x;
  if (tid < CH * NCLS / 4) ((float4*)sWl)[tid] = ((const float4*)Wl)[tid];
  if (tid < NCLS) sbl[tid] = bl[tid];
  __syncthreads();
  int row = blockIdx.x * 256 + tid;
  if (row >= N_VOX) return;
  float acc[NCLS];
#pragma unroll
  for (int j = 0; j < NCLS; j++) acc[j] = sbl[j];
#pragma unroll
  for (int q = 0; q < 4; q++) {
    uint4 a = A4[row * 4 + q], b = B4[row * 4 + q];
    unsigned int au[4] = {a.x, a.y, a.z, a.w}, bu[4] = {b.x, b.y, b.z, b.w};
#pragma unroll
    for (int t = 0; t < 4; t++) {
      int c = (q << 3) + (t << 1);
      float x0 = bf_lo(au[t]) + bf_lo(bu[t]);
      float x1 = bf_hi(au[t]) + bf_hi(bu[t]);
#pragma unroll
      for (int j = 0; j < NCLS; j++) {
        acc[j] = fmaf(x0, sWl[c * NCLS + j], acc[j]);
        acc[j] = fmaf(x1, sWl[(c + 1) * NCLS + j], acc[j]);
      }
    }
  }
  float4* op = (float4*)(out + row * NCLS);
#pragma unroll
  for (int j5 = 0; j5 < NCLS / 4; j5++) {
    float4 v = {acc[j5 * 4], acc[j5 * 4 + 1], acc[j5 * 4 + 2], acc[j5 * 4 + 3]};
    op[j5] = v;
  }
}

// ============================ launch ========================================
extern "C" void kernel_launch(void* const* d_in, const int* in_sizes, int n_in,
                              void* d_out, int out_size, void* d_ws, size_t ws_size,
                              hipStream_t stream) {
  const float* in_feats = (const float*)d_in[0];
  const int*   ga       = (const int*)d_in[1];
  const int*   sa       = (const int*)d_in[2];
  const int*   gb       = (const int*)d_in[3];
  const int*   sb       = (const int*)d_in[4];
  const float* w1       = (const float*)d_in[5];
  const float* b1       = (const float*)d_in[6];
  const float* w1_2     = (const float*)d_in[7];
  const float* b1_2     = (const float*)d_in[8];
  const float* w2       = (const float*)d_in[9];
  const float* b2       = (const float*)d_in[10];
  const float* w3       = (const float*)d_in[11];
  const float* b3       = (const float*)d_in[12];
  const float* wl       = (const float*)d_in[13];
  const float* bl       = (const float*)d_in[14];
  float* out = (float*)d_out;

  // ---- workspace carve-up (u32 units, ~74 MB total) ----
  unsigned int* wsu = (unsigned int*)d_ws;
  size_t o = 0;
  unsigned int* bufA = wsu + o; o += (size_t)MPAD * 16;
  unsigned int* bufB = wsu + o; o += (size_t)MPAD * 16;
  unsigned int* bufC = wsu + o; o += (size_t)MPAD * 16;
  unsigned int* inbf = wsu + o; o += (size_t)MPAD * 16;
  unsigned int* Wg1   = wsu + o; o += WG_U32;
  unsigned int* Wg1_2 = wsu + o; o += WG_U32;
  unsigned int* Wg2   = wsu + o; o += WG_U32;
  unsigned int* Wg3   = wsu + o; o += WG_U32;
  int* off_a = (int*)(wsu + o); o += MPAD;
  int* off_b = (int*)(wsu + o); o += MPAD;
  int* cnt_a = (int*)(wsu + o); o += MPAD;    // adjacent pair: one memset
  int* cnt_b = (int*)(wsu + o); o += MPAD;
  int* tmp   = (int*)(wsu + o); o += MPAD;
  int* part  = (int*)(wsu + o); o += 1024;
  int* pl_a  = (int*)(wsu + o); o += TOT;
  int* pl_b  = (int*)(wsu + o); o += TOT;

  dim3 blk(256);
  const int g_tot  = (TOT + 255) / 256;       // 15821
  const int g_pad  = NPART;                   // 586
  const int g_conv = MPAD / 64;               // 2344
  const int g_wp   = (WG_U32 + 255) / 256;    // 54
  const int g_bf   = 2344;                    // 600000/256
  const int g_lg   = (N_VOX + 255) / 256;     // 586

  // ---- build inverted CSRs (no leveling) ----
  hipMemsetAsync(cnt_a, 0, 2 * (size_t)MPAD * sizeof(int), stream);
  k_hist<<<g_tot, blk, 0, stream>>>(sa, cnt_a);
  k_hist<<<g_tot, blk, 0, stream>>>(sb, cnt_b);
  k_scan1<<<g_pad, blk, 0, stream>>>(cnt_a, tmp, part);
  k_scan2<<<1, 1024, 0, stream>>>(part);
  k_scan3<<<g_pad, blk, 0, stream>>>(tmp, part, off_a);
  k_scan1<<<g_pad, blk, 0, stream>>>(cnt_b, tmp, part);
  k_scan2<<<1, 1024, 0, stream>>>(part);
  k_scan3<<<g_pad, blk, 0, stream>>>(tmp, part, off_b);
  hipMemsetAsync(cnt_a, 0, 2 * (size_t)MPAD * sizeof(int), stream);
  k_fill<<<g_tot, blk, 0, stream>>>(ga, sa, off_a, cnt_a, pl_a);
  k_fill<<<g_tot, blk, 0, stream>>>(gb, sb, off_b, cnt_b, pl_b);

  // ---- weight prep + activation convert ----
  k_wprep<<<g_wp, blk, 0, stream>>>(w1,   Wg1);
  k_wprep<<<g_wp, blk, 0, stream>>>(w1_2, Wg1_2);
  k_wprep<<<g_wp, blk, 0, stream>>>(w2,   Wg2);
  k_wprep<<<g_wp, blk, 0, stream>>>(w3,   Wg3);
  k_tobf<<<g_bf, blk, 0, stream>>>((const float4*)in_feats, (uint4*)inbf);

  // ---- 4 MFMA conv layers ----
  k_conv<<<g_conv, blk, 0, stream>>>((const uint4*)inbf, bufA, off_a, pl_a,
                                     (const uint4*)Wg1, b1);
  k_conv<<<g_conv, blk, 0, stream>>>((const uint4*)bufA, bufB, off_b, pl_b,
                                     (const uint4*)Wg1_2, b1_2);
  k_conv<<<g_conv, blk, 0, stream>>>((const uint4*)inbf, bufC, off_b, pl_b,
                                     (const uint4*)Wg2, b2);
  k_conv<<<g_conv, blk, 0, stream>>>((const uint4*)bufC, bufA, off_a, pl_a,
                                     (const uint4*)Wg3, b3);

  // ---- logits ----
  k_logits<<<g_lg, blk, 0, stream>>>((const uint4*)bufB, (const uint4*)bufA,
                                     wl, bl, out);
}